// Round 3
// baseline (516.636 us; speedup 1.0000x reference)
//
#include <hip/hip_runtime.h>
#include <math.h>
#include <stdint.h>

#define Bsz 8
#define Lsz 8192
#define D 256
#define NROWS (Bsz*Lsz)      // 65536
#define NC 128               // chunks per sequence
#define CL (Lsz/NC)          // 64
#define LN_EPS 1e-6f

typedef float f32x4 __attribute__((ext_vector_type(4)));
typedef short bf16x8 __attribute__((ext_vector_type(8)));
typedef uint32_t __attribute__((address_space(3))) as3_u32;
typedef const uint32_t __attribute__((address_space(1))) as1_u32;

__device__ __forceinline__ float gelu_tanh(float v){
    const float k0 = 0.7978845608028654f;   // sqrt(2/pi)
    const float k1 = 0.044715f;
    float inner = k0 * fmaf(k1*v*v, v, v);
    return 0.5f * v * (1.0f + tanhf(inner));
}
__device__ __forceinline__ uint16_t bf16_rne(float f){
    uint32_t u = __float_as_uint(f);
    return (uint16_t)((u + 0x7fffu + ((u>>16)&1u)) >> 16);
}
__device__ __forceinline__ float bf16_to_f(uint16_t h){
    return __uint_as_float(((uint32_t)h)<<16);
}

// ---- prep: split weights to bf16 hi/lo planes (B-layout [N][K]) ------------
// b1 [512][256]: n<256 -> B_re, else B_im ; value *= ln_scale[d]
// b2 [256][512]: k=2h -> C_re[n][h], k=2h+1 -> -C_im[n][h]  (K interleaved to
//                match the scan's in-place (re,im)-paired h planes)
// b3 [256][256]: W
__global__ __launch_bounds__(256)
void k_prep(const float* __restrict__ B_re, const float* __restrict__ B_im,
            const float* __restrict__ C_re, const float* __restrict__ C_im,
            const float* __restrict__ W, const float* __restrict__ ln_scale,
            short* __restrict__ b1_hi, short* __restrict__ b1_lo,
            short* __restrict__ b2_hi, short* __restrict__ b2_lo,
            short* __restrict__ b3_hi, short* __restrict__ b3_lo){
    int i = blockIdx.x*256 + threadIdx.x;   // 131072
    {   // b1
        int n = i >> 8, d = i & 255;
        float v = (n < 256 ? B_re[n*256 + d] : B_im[(n-256)*256 + d]) * ln_scale[d];
        uint16_t hi = bf16_rne(v);
        b1_hi[i] = (short)hi;
        b1_lo[i] = (short)bf16_rne(v - bf16_to_f(hi));
    }
    {   // b2 (K-interleaved re/im)
        int n = i >> 9, k = i & 511, h = k >> 1;
        float v = (k & 1) ? -C_im[n*256 + h] : C_re[n*256 + h];
        uint16_t hi = bf16_rne(v);
        b2_hi[i] = (short)hi;
        b2_lo[i] = (short)bf16_rne(v - bf16_to_f(hi));
    }
    if (i < 256*256){   // b3
        float v = W[i];
        uint16_t hi = bf16_rne(v);
        b3_hi[i] = (short)hi;
        b3_lo[i] = (short)bf16_rne(v - bf16_to_f(hi));
    }
}

// t1[n] = sum_d ln_scale[d]*B1[n][d] ; t2[n] = sum_d ln_bias[d]*B1[n][d]
__global__ __launch_bounds__(256)
void k_prep_t(const float* __restrict__ B_re, const float* __restrict__ B_im,
              const float* __restrict__ ln_scale, const float* __restrict__ ln_bias,
              float* __restrict__ t1, float* __restrict__ t2){
    int n = blockIdx.x*256 + threadIdx.x;
    if (n >= 512) return;
    const float* src = (n < 256) ? &B_re[n*256] : &B_im[(n-256)*256];
    float s1 = 0.f, s2 = 0.f;
    for (int d = 0; d < 256; d++){
        float b = src[d];
        s1 = fmaf(ln_scale[d], b, s1);
        s2 = fmaf(ln_bias[d],  b, s2);
    }
    t1[n] = s1; t2[n] = s2;
}

// ---- stats: LN (mu, rstd) per row + materialize xhi/xlo bf16 planes --------
__global__ __launch_bounds__(256)
void k_stats(const float* __restrict__ x, float* __restrict__ mu_arr,
             float* __restrict__ rstd_arr, short* __restrict__ xhi,
             short* __restrict__ xlo){
    int r0 = blockIdx.x * 16;
    int t = threadIdx.x;
    int wave = t >> 6, lane = t & 63;
    for (int rr = wave; rr < 16; rr += 4){
        const float* xr = x + (size_t)(r0 + rr) * D;
        float v[4]; float s = 0.f;
        #pragma unroll
        for (int i=0;i<4;i++){ v[i] = xr[lane + 64*i]; s += v[i]; }
        #pragma unroll
        for (int off=32; off; off>>=1) s += __shfl_xor(s, off);
        float mu = s * (1.0f/D);
        float vs = 0.f;
        #pragma unroll
        for (int i=0;i<4;i++){ float dd = v[i]-mu; vs += dd*dd; }
        #pragma unroll
        for (int off=32; off; off>>=1) vs += __shfl_xor(vs, off);
        float rstd = rsqrtf(vs*(1.0f/D) + LN_EPS);
        if (lane == 0){ mu_arr[r0+rr] = mu; rstd_arr[r0+rr] = rstd; }
        size_t rb = (size_t)(r0+rr)*D;
        #pragma unroll
        for (int i=0;i<4;i++){
            int dd = lane + 64*i;
            uint16_t hb = bf16_rne(v[i]);
            xhi[rb+dd] = (short)hb;
            xlo[rb+dd] = (short)bf16_rne(v[i] - bf16_to_f(hb));
        }
    }
}

// ---- unified 128x128 MFMA GEMM, m97-style global_load_lds staging ----------
// A (hi/lo planes, [M][K] bf16) x B (hi/lo, [N][K] bf16), 3-product split:
//   C = Ahi*Bhi + Ahi*Blo + Alo*Bhi
// MODE 1: K=256, A=x-planes, N=512 -> bu_re/bu_im fp32 with LN fold + gamma
// MODE 2: K=512, A=h-planes (re/im K-interleaved), N=256 -> gelu -> g planes
// MODE 3: K=256, A=g-planes, N=256 -> +b +x -> out
#define GLD16(gp, lp) __builtin_amdgcn_global_load_lds((as1_u32*)(gp), (as3_u32*)(lp), 16, 0, 0)

template<int MODE>
__global__ __launch_bounds__(256)
void k_gemm(const short* __restrict__ Ahi_g, const short* __restrict__ Alo_g,
            const short* __restrict__ Bhi_g, const short* __restrict__ Blo_g,
            const float* __restrict__ x,
            const float* __restrict__ mu_arr, const float* __restrict__ rs_arr,
            const float* __restrict__ t1, const float* __restrict__ t2,
            const float* __restrict__ nu_log,
            const float* __restrict__ ln_scale, const float* __restrict__ ln_bias,
            const float* __restrict__ d_skip, const float* __restrict__ bvec,
            float* __restrict__ outA, float* __restrict__ outB,
            short* __restrict__ gh, short* __restrict__ gl){
    constexpr int K = (MODE==2) ? 512 : 256;
    __shared__ __align__(16) short Ah[128*32];
    __shared__ __align__(16) short Al[128*32];
    __shared__ __align__(16) short Bh[128*32];
    __shared__ __align__(16) short Bl[128*32];
    const int t = threadIdx.x;
    const int w = t >> 6, lane = t & 63;
    const int lgrp = lane >> 4, lrow = lane & 15;
    const int r0 = blockIdx.x * 128;
    const int n0 = blockIdx.y * 128;
    const int mr = (w >> 1) * 64;      // wave row base in tile
    const int nc = (w & 1) * 64;       // wave col base in tile

    // staging: thread t covers LDS bytes [16t,16t+16) of issue0, +4KB issue1
    const int srow = t >> 2;           // 0..63
    const int scol = (t & 3) * 8;
    const short* pah = Ahi_g + (size_t)(r0+srow)*K + scol;
    const short* pal = Alo_g + (size_t)(r0+srow)*K + scol;
    const short* pbh = Bhi_g + (size_t)(n0+srow)*K + scol;
    const short* pbl = Blo_g + (size_t)(n0+srow)*K + scol;
    const size_t rowhop = (size_t)64 * K;   // +64 rows for issue1
    // wave-uniform LDS dests (issue i: + i*2048 shorts, wave w: + w*512 shorts)
    short* dAh0 = &Ah[w*512]; short* dAh1 = &Ah[2048 + w*512];
    short* dAl0 = &Al[w*512]; short* dAl1 = &Al[2048 + w*512];
    short* dBh0 = &Bh[w*512]; short* dBh1 = &Bh[2048 + w*512];
    short* dBl0 = &Bl[w*512]; short* dBl1 = &Bl[2048 + w*512];

    f32x4 acc[4][4];
    #pragma unroll
    for (int mf=0;mf<4;mf++)
    #pragma unroll
    for (int nf=0;nf<4;nf++) acc[mf][nf] = (f32x4){0.f,0.f,0.f,0.f};

    for (int k0 = 0; k0 < K; k0 += 32){
        __syncthreads();
        GLD16(pah + k0,          dAh0);
        GLD16(pah + rowhop + k0, dAh1);
        GLD16(pal + k0,          dAl0);
        GLD16(pal + rowhop + k0, dAl1);
        GLD16(pbh + k0,          dBh0);
        GLD16(pbh + rowhop + k0, dBh1);
        GLD16(pbl + k0,          dBl0);
        GLD16(pbl + rowhop + k0, dBl1);
        __syncthreads();

        bf16x8 ahv[4], alv[4], bhv[4], blv[4];
        #pragma unroll
        for (int mf=0;mf<4;mf++){
            ahv[mf] = *(const bf16x8*)&Ah[(mr + mf*16 + lrow)*32 + lgrp*8];
            alv[mf] = *(const bf16x8*)&Al[(mr + mf*16 + lrow)*32 + lgrp*8];
        }
        #pragma unroll
        for (int nf=0;nf<4;nf++){
            bhv[nf] = *(const bf16x8*)&Bh[(nc + nf*16 + lrow)*32 + lgrp*8];
            blv[nf] = *(const bf16x8*)&Bl[(nc + nf*16 + lrow)*32 + lgrp*8];
        }
        #pragma unroll
        for (int mf=0;mf<4;mf++)
        #pragma unroll
        for (int nf=0;nf<4;nf++){
            acc[mf][nf] = __builtin_amdgcn_mfma_f32_16x16x32_bf16(ahv[mf], bhv[nf], acc[mf][nf], 0,0,0);
            acc[mf][nf] = __builtin_amdgcn_mfma_f32_16x16x32_bf16(ahv[mf], blv[nf], acc[mf][nf], 0,0,0);
            acc[mf][nf] = __builtin_amdgcn_mfma_f32_16x16x32_bf16(alv[mf], bhv[nf], acc[mf][nf], 0,0,0);
        }
    }

    // ---- epilogue ----
    #pragma unroll
    for (int nf=0; nf<4; nf++){
        const int col = n0 + nc + nf*16 + lrow;      // MODE1: 0..511 else 0..255
        if (MODE == 1){
            float gam = sqrtf(1.0f - expf(-2.0f*expf(nu_log[col & 255])));
            float t1v = t1[col], t2v = t2[col];
            float* dst = (col < 256) ? outA : outB;
            int c2 = col & 255;
            #pragma unroll
            for (int mf=0;mf<4;mf++){
                #pragma unroll
                for (int j=0;j<4;j++){
                    int row = r0 + mr + mf*16 + lgrp*4 + j;
                    float rs = rs_arr[row], muv = mu_arr[row];
                    dst[(size_t)row*256 + c2] = gam * (rs*acc[mf][nf][j] - rs*muv*t1v + t2v);
                }
            }
        } else if (MODE == 2){
            float dsk = d_skip[col], sc = ln_scale[col], bi = ln_bias[col];
            #pragma unroll
            for (int mf=0;mf<4;mf++){
                #pragma unroll
                for (int j=0;j<4;j++){
                    int row = r0 + mr + mf*16 + lgrp*4 + j;
                    size_t idx = (size_t)row*256 + col;
                    float rs = rs_arr[row], muv = mu_arr[row];
                    float xn = (x[idx] - muv)*rs*sc + bi;
                    float g = gelu_tanh(acc[mf][nf][j] + dsk*xn);
                    uint16_t hb = bf16_rne(g);
                    gh[idx] = (short)hb;
                    gl[idx] = (short)bf16_rne(g - bf16_to_f(hb));
                }
            }
        } else {
            float bb = bvec[col];
            #pragma unroll
            for (int mf=0;mf<4;mf++){
                #pragma unroll
                for (int j=0;j<4;j++){
                    int row = r0 + mr + mf*16 + lgrp*4 + j;
                    size_t idx = (size_t)row*256 + col;
                    outA[idx] = acc[mf][nf][j] + bb + x[idx];
                }
            }
        }
    }
}

// ---- scan kernels ----------------------------------------------------------
__global__ __launch_bounds__(256)
void k_scan_local(const float* __restrict__ nu_log, const float* __restrict__ theta_log,
                  const float* __restrict__ bu_re, const float* __restrict__ bu_im,
                  float* __restrict__ e_re, float* __restrict__ e_im){
    int h = threadIdx.x;
    int bc = blockIdx.x;
    int b = bc / NC, c = bc % NC;
    float en = expf(nu_log[h]);
    float mag = expf(-en), th = expf(theta_log[h]);
    float lam_re = mag * cosf(th), lam_im = mag * sinf(th);
    const float* pr = bu_re + (size_t)(b*Lsz + c*CL)*D + h;
    const float* pi = bu_im + (size_t)(b*Lsz + c*CL)*D + h;
    float sr = 0.f, si = 0.f;
    #pragma unroll 4
    for (int tt=0; tt<CL; tt++){
        float ur = pr[(size_t)tt*D], ui = pi[(size_t)tt*D];
        float nsr = fmaf(lam_re, sr, fmaf(-lam_im, si, ur));
        float nsi = fmaf(lam_re, si, fmaf( lam_im, sr, ui));
        sr = nsr; si = nsi;
    }
    e_re[(c*Bsz + b)*D + h] = sr;
    e_im[(c*Bsz + b)*D + h] = si;
}

__global__ __launch_bounds__(256)
void k_scan_combine(const float* __restrict__ nu_log, const float* __restrict__ theta_log,
                    const float* __restrict__ e_re, const float* __restrict__ e_im,
                    float* __restrict__ p_re, float* __restrict__ p_im){
    int h = threadIdx.x;
    int b = blockIdx.x;
    double en = exp((double)nu_log[h]);
    double th = exp((double)theta_log[h]);
    double mag = exp(-en);
    double lr = mag*cos(th), li = mag*sin(th);
    double ar = 1.0, ai = 0.0;               // lam^CL
    for (int i=0;i<CL;i++){
        double nr = ar*lr - ai*li;
        double ni = ar*li + ai*lr;
        ar = nr; ai = ni;
    }
    double sr = 0.0, si = 0.0;
    for (int c=0;c<NC;c++){
        int idx = (c*Bsz + b)*D + h;
        p_re[idx] = (float)sr; p_im[idx] = (float)si;
        double er = e_re[idx], ei = e_im[idx];
        double nr = ar*sr - ai*si + er;
        double ni = ar*si + ai*sr + ei;
        sr = nr; si = ni;
    }
}

// re-scan with prefix; write h IN PLACE over bu planes as bf16 pairs:
//   bu_re dword(col h) <- (bf16(h_re), bf16(h_im))   [hi plane, K-interleaved]
//   bu_im dword(col h) <- (lo residuals)             [lo plane]
__global__ __launch_bounds__(256)
void k_scan_apply(const float* __restrict__ nu_log, const float* __restrict__ theta_log,
                  const float* __restrict__ p_re, const float* __restrict__ p_im,
                  float* __restrict__ bu_re, float* __restrict__ bu_im){
    int h = threadIdx.x;
    int bc = blockIdx.x;
    int b = bc / NC, c = bc % NC;
    float en = expf(nu_log[h]);
    float mag = expf(-en), th = expf(theta_log[h]);
    float lam_re = mag * cosf(th), lam_im = mag * sinf(th);
    int pidx = (c*Bsz + b)*D + h;
    float sr = p_re[pidx], si = p_im[pidx];
    float* pr = bu_re + (size_t)(b*Lsz + c*CL)*D + h;
    float* pi = bu_im + (size_t)(b*Lsz + c*CL)*D + h;
    #pragma unroll 4
    for (int tt=0; tt<CL; tt++){
        float ur = pr[(size_t)tt*D], ui = pi[(size_t)tt*D];
        float nsr = fmaf(lam_re, sr, fmaf(-lam_im, si, ur));
        float nsi = fmaf(lam_re, si, fmaf( lam_im, sr, ui));
        sr = nsr; si = nsi;
        uint16_t rh = bf16_rne(sr), ih = bf16_rne(si);
        uint16_t rl = bf16_rne(sr - bf16_to_f(rh));
        uint16_t il = bf16_rne(si - bf16_to_f(ih));
        *(uint32_t*)&pr[(size_t)tt*D] = (uint32_t)rh | ((uint32_t)ih << 16);
        *(uint32_t*)&pi[(size_t)tt*D] = (uint32_t)rl | ((uint32_t)il << 16);
    }
}

extern "C" void kernel_launch(void* const* d_in, const int* in_sizes, int n_in,
                              void* d_out, int out_size, void* d_ws, size_t ws_size,
                              hipStream_t stream){
    const float* x         = (const float*)d_in[0];
    const float* ln_scale  = (const float*)d_in[1];
    const float* ln_bias   = (const float*)d_in[2];
    const float* nu_log    = (const float*)d_in[3];
    const float* theta_log = (const float*)d_in[4];
    const float* B_re      = (const float*)d_in[5];
    const float* B_im      = (const float*)d_in[6];
    const float* C_re      = (const float*)d_in[7];
    const float* C_im      = (const float*)d_in[8];
    const float* D_skip    = (const float*)d_in[9];
    const float* W         = (const float*)d_in[10];
    const float* bvec      = (const float*)d_in[11];
    float* out = (float*)d_out;

    char* base = (char*)d_ws;
    size_t off = 0;
    auto alloc = [&](size_t bytes)->char*{
        char* p = base + off;
        off += (bytes + 255) & ~(size_t)255;
        return p;
    };
    float*  bu_re = (float*)alloc((size_t)NROWS*D*4);   // later: h hi-plane
    float*  bu_im = (float*)alloc((size_t)NROWS*D*4);   // later: h lo-plane
    short*  xg_hi = (short*)alloc((size_t)NROWS*D*2);   // xhi, later ghi
    short*  xg_lo = (short*)alloc((size_t)NROWS*D*2);   // xlo, later glo
    float*  mu_a  = (float*)alloc((size_t)NROWS*4);
    float*  rs_a  = (float*)alloc((size_t)NROWS*4);
    float*  e_re  = (float*)alloc((size_t)NC*Bsz*D*4);
    float*  e_im  = (float*)alloc((size_t)NC*Bsz*D*4);
    float*  p_re  = (float*)alloc((size_t)NC*Bsz*D*4);
    float*  p_im  = (float*)alloc((size_t)NC*Bsz*D*4);
    float*  t1    = (float*)alloc(512*4);
    float*  t2    = (float*)alloc(512*4);
    short*  b1_hi = (short*)alloc(512*256*2);
    short*  b1_lo = (short*)alloc(512*256*2);
    short*  b2_hi = (short*)alloc(256*512*2);
    short*  b2_lo = (short*)alloc(256*512*2);
    short*  b3_hi = (short*)alloc(256*256*2);
    short*  b3_lo = (short*)alloc(256*256*2);

    k_prep<<<512, 256, 0, stream>>>(B_re, B_im, C_re, C_im, W, ln_scale,
                                    b1_hi, b1_lo, b2_hi, b2_lo, b3_hi, b3_lo);
    k_prep_t<<<2, 256, 0, stream>>>(B_re, B_im, ln_scale, ln_bias, t1, t2);
    k_stats<<<NROWS/16, 256, 0, stream>>>(x, mu_a, rs_a, xg_hi, xg_lo);

    // GEMM1: Bu = gamma*(LN(x) @ B1^T)   (N=512: cols 0-255 re, 256-511 im)
    k_gemm<1><<<dim3(NROWS/128, 4), 256, 0, stream>>>(
        xg_hi, xg_lo, b1_hi, b1_lo, x, mu_a, rs_a, t1, t2, nu_log,
        ln_scale, ln_bias, D_skip, bvec, bu_re, bu_im, nullptr, nullptr);

    k_scan_local<<<Bsz*NC, 256, 0, stream>>>(nu_log, theta_log, bu_re, bu_im, e_re, e_im);
    k_scan_combine<<<Bsz, 256, 0, stream>>>(nu_log, theta_log, e_re, e_im, p_re, p_im);
    k_scan_apply<<<Bsz*NC, 256, 0, stream>>>(nu_log, theta_log, p_re, p_im, bu_re, bu_im);

    // GEMM2: y = Re(h C^T) + Dskip*xn -> gelu -> g planes (alias x-planes)
    k_gemm<2><<<dim3(NROWS/128, 2), 256, 0, stream>>>(
        (const short*)bu_re, (const short*)bu_im, b2_hi, b2_lo, x,
        mu_a, rs_a, t1, t2, nu_log, ln_scale, ln_bias, D_skip, bvec,
        nullptr, nullptr, xg_hi, xg_lo);

    // GEMM3: out = g W^T + b + x
    k_gemm<3><<<dim3(NROWS/128, 2), 256, 0, stream>>>(
        xg_hi, xg_lo, b3_hi, b3_lo, x, mu_a, rs_a, t1, t2, nu_log,
        ln_scale, ln_bias, D_skip, bvec, out, nullptr, nullptr, nullptr);
}

// Round 4
// 480.261 us; speedup vs baseline: 1.0757x; 1.0757x over previous
//
#include <hip/hip_runtime.h>
#include <math.h>
#include <stdint.h>

#define Bsz 8
#define Lsz 8192
#define D 256
#define NROWS (Bsz*Lsz)      // 65536
#define NC 128               // chunks per sequence
#define CL (Lsz/NC)          // 64
#define LN_EPS 1e-6f

typedef float f32x4 __attribute__((ext_vector_type(4)));
typedef short bf16x8 __attribute__((ext_vector_type(8)));
typedef uint32_t __attribute__((address_space(3))) as3_u32;
typedef const uint32_t __attribute__((address_space(1))) as1_u32;

__device__ __forceinline__ float gelu_tanh(float v){
    const float k0 = 0.7978845608028654f;   // sqrt(2/pi)
    const float k1 = 0.044715f;
    float inner = k0 * fmaf(k1*v*v, v, v);
    return 0.5f * v * (1.0f + tanhf(inner));
}
__device__ __forceinline__ uint16_t bf16_rne(float f){
    uint32_t u = __float_as_uint(f);
    return (uint16_t)((u + 0x7fffu + ((u>>16)&1u)) >> 16);
}
__device__ __forceinline__ float bf16_to_f(uint16_t h){
    return __uint_as_float(((uint32_t)h)<<16);
}

// ---- prep: split weights to bf16 hi/lo planes (B-layout [N][K]) ------------
__global__ __launch_bounds__(256)
void k_prep(const float* __restrict__ B_re, const float* __restrict__ B_im,
            const float* __restrict__ C_re, const float* __restrict__ C_im,
            const float* __restrict__ W, const float* __restrict__ ln_scale,
            short* __restrict__ b1_hi, short* __restrict__ b1_lo,
            short* __restrict__ b2_hi, short* __restrict__ b2_lo,
            short* __restrict__ b3_hi, short* __restrict__ b3_lo){
    int i = blockIdx.x*256 + threadIdx.x;   // 131072
    {   // b1 [512][256]
        int n = i >> 8, d = i & 255;
        float v = (n < 256 ? B_re[n*256 + d] : B_im[(n-256)*256 + d]) * ln_scale[d];
        uint16_t hi = bf16_rne(v);
        b1_hi[i] = (short)hi;
        b1_lo[i] = (short)bf16_rne(v - bf16_to_f(hi));
    }
    {   // b2 [256][512], K-interleaved re/im
        int n = i >> 9, k = i & 511, h = k >> 1;
        float v = (k & 1) ? -C_im[n*256 + h] : C_re[n*256 + h];
        uint16_t hi = bf16_rne(v);
        b2_hi[i] = (short)hi;
        b2_lo[i] = (short)bf16_rne(v - bf16_to_f(hi));
    }
    if (i < 256*256){   // b3 [256][256]
        float v = W[i];
        uint16_t hi = bf16_rne(v);
        b3_hi[i] = (short)hi;
        b3_lo[i] = (short)bf16_rne(v - bf16_to_f(hi));
    }
}

__global__ __launch_bounds__(256)
void k_prep_t(const float* __restrict__ B_re, const float* __restrict__ B_im,
              const float* __restrict__ ln_scale, const float* __restrict__ ln_bias,
              float* __restrict__ t1, float* __restrict__ t2){
    int n = blockIdx.x*256 + threadIdx.x;
    if (n >= 512) return;
    const float* src = (n < 256) ? &B_re[n*256] : &B_im[(n-256)*256];
    float s1 = 0.f, s2 = 0.f;
    for (int d = 0; d < 256; d++){
        float b = src[d];
        s1 = fmaf(ln_scale[d], b, s1);
        s2 = fmaf(ln_bias[d],  b, s2);
    }
    t1[n] = s1; t2[n] = s2;
}

// ---- stats: LN (mu, rstd) per row + materialize xhi/xlo bf16 planes --------
__global__ __launch_bounds__(256)
void k_stats(const float* __restrict__ x, float* __restrict__ mu_arr,
             float* __restrict__ rstd_arr, short* __restrict__ xhi,
             short* __restrict__ xlo){
    int r0 = blockIdx.x * 16;
    int t = threadIdx.x;
    int wave = t >> 6, lane = t & 63;
    for (int rr = wave; rr < 16; rr += 4){
        const float* xr = x + (size_t)(r0 + rr) * D;
        float v[4]; float s = 0.f;
        #pragma unroll
        for (int i=0;i<4;i++){ v[i] = xr[lane + 64*i]; s += v[i]; }
        #pragma unroll
        for (int off=32; off; off>>=1) s += __shfl_xor(s, off);
        float mu = s * (1.0f/D);
        float vs = 0.f;
        #pragma unroll
        for (int i=0;i<4;i++){ float dd = v[i]-mu; vs += dd*dd; }
        #pragma unroll
        for (int off=32; off; off>>=1) vs += __shfl_xor(vs, off);
        float rstd = rsqrtf(vs*(1.0f/D) + LN_EPS);
        if (lane == 0){ mu_arr[r0+rr] = mu; rstd_arr[r0+rr] = rstd; }
        size_t rb = (size_t)(r0+rr)*D;
        #pragma unroll
        for (int i=0;i<4;i++){
            int dd = lane + 64*i;
            uint16_t hb = bf16_rne(v[i]);
            xhi[rb+dd] = (short)hb;
            xlo[rb+dd] = (short)bf16_rne(v[i] - bf16_to_f(hb));
        }
    }
}

// ---- 128x128 MFMA GEMM: 2-phase dbuf pipeline + fragment-major LDS ---------
// LDS layout per 8KB tile = 512 chunks of 16B; chunk c = g*64 + kg*16 + r16
// holds rows g*16+r16, k-shorts kg*8..+7 -> each wave's frag read is 1KB
// contiguous (zero bank conflicts). Staged via global_load_lds with
// pre-permuted per-lane SOURCE addresses (LDS dest stays linear).
#define GLD16(gp, lp) __builtin_amdgcn_global_load_lds((as1_u32*)(gp), (as3_u32*)(lp), 16, 0, 0)

template<int MODE>
__global__ __launch_bounds__(256)
void k_gemm(const short* __restrict__ Ahi_g, const short* __restrict__ Alo_g,
            const short* __restrict__ Bhi_g, const short* __restrict__ Blo_g,
            const float* __restrict__ x,
            const float* __restrict__ mu_arr, const float* __restrict__ rs_arr,
            const float* __restrict__ t1, const float* __restrict__ t2,
            const float* __restrict__ nu_log,
            const float* __restrict__ ln_scale, const float* __restrict__ ln_bias,
            const float* __restrict__ d_skip, const float* __restrict__ bvec,
            float* __restrict__ outA, float* __restrict__ outB,
            short* __restrict__ gh, short* __restrict__ gl){
    constexpr int K   = (MODE==2) ? 512 : 256;
    constexpr int NYB = (MODE==1) ? 4 : 2;
    constexpr int NT  = K/32;
    __shared__ __align__(16) short Ah[2][4096];
    __shared__ __align__(16) short Al[2][4096];
    __shared__ __align__(16) short Bh[2][4096];
    __shared__ __align__(16) short Bl[2][4096];
    const int t = threadIdx.x;
    const int w = t >> 6, lane = t & 63;
    const int lgrp = lane >> 4, lrow = lane & 15;
    const int r0 = (blockIdx.x / NYB) * 128;   // y-fastest: co-resident share A
    const int n0 = (blockIdx.x % NYB) * 128;
    const int mr = (w >> 1) * 64;
    const int nc = (w & 1) * 64;

    // staging: call i, wave w, lane l covers chunk c = i*256 + w*64 + l
    //   -> global row (i*4+w)*16 + (l&15), k-shorts ((l>>4)&3)*8
    const int srow = w*16 + lrow;
    const int scol = lgrp*8;
    const short* pa_h = Ahi_g + (size_t)(r0+srow)*K + scol;
    const short* pa_l = Alo_g + (size_t)(r0+srow)*K + scol;
    const short* pb_h = Bhi_g + (size_t)(n0+srow)*K + scol;
    const short* pb_l = Blo_g + (size_t)(n0+srow)*K + scol;
    const size_t hop = (size_t)64*K;           // +64 rows for call 1
    const int d0 = w*512;                      // LDS chunk base (shorts), call 0
    const int d1 = 2048 + w*512;               // call 1

    f32x4 acc[4][4];
    #pragma unroll
    for (int mf=0;mf<4;mf++)
    #pragma unroll
    for (int nf=0;nf<4;nf++) acc[mf][nf] = (f32x4){0.f,0.f,0.f,0.f};

    auto stage = [&](int kt, int buf){
        const int k0 = kt*32;
        GLD16(pa_h + k0,       &Ah[buf][d0]);
        GLD16(pa_h + hop + k0, &Ah[buf][d1]);
        GLD16(pa_l + k0,       &Al[buf][d0]);
        GLD16(pa_l + hop + k0, &Al[buf][d1]);
        GLD16(pb_h + k0,       &Bh[buf][d0]);
        GLD16(pb_h + hop + k0, &Bh[buf][d1]);
        GLD16(pb_l + k0,       &Bl[buf][d0]);
        GLD16(pb_l + hop + k0, &Bl[buf][d1]);
    };

    stage(0, 0);
    __syncthreads();
    int cur = 0;
    const int ga = (w>>1)*4, gb = (w&1)*4;
    for (int kt = 0; kt < NT; ++kt){
        if (kt+1 < NT) stage(kt+1, cur^1);     // prefetch overlaps compute
        bf16x8 ahv[4], alv[4], bhv[4], blv[4];
        #pragma unroll
        for (int mf=0;mf<4;mf++){
            const int c = ((ga+mf)*64 + lgrp*16 + lrow)*8;
            ahv[mf] = *(const bf16x8*)&Ah[cur][c];
            alv[mf] = *(const bf16x8*)&Al[cur][c];
        }
        #pragma unroll
        for (int nf=0;nf<4;nf++){
            const int c = ((gb+nf)*64 + lgrp*16 + lrow)*8;
            bhv[nf] = *(const bf16x8*)&Bh[cur][c];
            blv[nf] = *(const bf16x8*)&Bl[cur][c];
        }
        #pragma unroll
        for (int mf=0;mf<4;mf++)
        #pragma unroll
        for (int nf=0;nf<4;nf++){
            acc[mf][nf] = __builtin_amdgcn_mfma_f32_16x16x32_bf16(ahv[mf], bhv[nf], acc[mf][nf], 0,0,0);
            acc[mf][nf] = __builtin_amdgcn_mfma_f32_16x16x32_bf16(ahv[mf], blv[nf], acc[mf][nf], 0,0,0);
            acc[mf][nf] = __builtin_amdgcn_mfma_f32_16x16x32_bf16(alv[mf], bhv[nf], acc[mf][nf], 0,0,0);
        }
        __syncthreads();                       // drains prefetch vmcnt + lgkm
        cur ^= 1;
    }

    // ---- epilogue ----
    #pragma unroll
    for (int nf=0; nf<4; nf++){
        const int col = n0 + nc + nf*16 + lrow;
        if (MODE == 1){
            float gam = sqrtf(1.0f - expf(-2.0f*expf(nu_log[col & 255])));
            float t1v = t1[col], t2v = t2[col];
            float* dst = (col < 256) ? outA : outB;
            int c2 = col & 255;
            #pragma unroll
            for (int mf=0;mf<4;mf++){
                #pragma unroll
                for (int j=0;j<4;j++){
                    int row = r0 + mr + mf*16 + lgrp*4 + j;
                    float rs = rs_arr[row], muv = mu_arr[row];
                    dst[(size_t)row*256 + c2] = gam * (rs*acc[mf][nf][j] - rs*muv*t1v + t2v);
                }
            }
        } else if (MODE == 2){
            float dsk = d_skip[col], sc = ln_scale[col], bi = ln_bias[col];
            #pragma unroll
            for (int mf=0;mf<4;mf++){
                #pragma unroll
                for (int j=0;j<4;j++){
                    int row = r0 + mr + mf*16 + lgrp*4 + j;
                    size_t idx = (size_t)row*256 + col;
                    float rs = rs_arr[row], muv = mu_arr[row];
                    float xn = (x[idx] - muv)*rs*sc + bi;
                    float g = gelu_tanh(acc[mf][nf][j] + dsk*xn);
                    uint16_t hb = bf16_rne(g);
                    gh[idx] = (short)hb;
                    gl[idx] = (short)bf16_rne(g - bf16_to_f(hb));
                }
            }
        } else {
            float bb = bvec[col];
            #pragma unroll
            for (int mf=0;mf<4;mf++){
                #pragma unroll
                for (int j=0;j<4;j++){
                    int row = r0 + mr + mf*16 + lgrp*4 + j;
                    size_t idx = (size_t)row*256 + col;
                    outA[idx] = acc[mf][nf][j] + bb + x[idx];
                }
            }
        }
    }
}

// ---- scan kernels ----------------------------------------------------------
__global__ __launch_bounds__(256)
void k_scan_local(const float* __restrict__ nu_log, const float* __restrict__ theta_log,
                  const float* __restrict__ bu_re, const float* __restrict__ bu_im,
                  float* __restrict__ e_re, float* __restrict__ e_im){
    int h = threadIdx.x;
    int bc = blockIdx.x;
    int b = bc / NC, c = bc % NC;
    float en = expf(nu_log[h]);
    float mag = expf(-en), th = expf(theta_log[h]);
    float lam_re = mag * cosf(th), lam_im = mag * sinf(th);
    const float* pr = bu_re + (size_t)(b*Lsz + c*CL)*D + h;
    const float* pi = bu_im + (size_t)(b*Lsz + c*CL)*D + h;
    float sr = 0.f, si = 0.f;
    #pragma unroll 4
    for (int tt=0; tt<CL; tt++){
        float ur = pr[(size_t)tt*D], ui = pi[(size_t)tt*D];
        float nsr = fmaf(lam_re, sr, fmaf(-lam_im, si, ur));
        float nsi = fmaf(lam_re, si, fmaf( lam_im, sr, ui));
        sr = nsr; si = nsi;
    }
    e_re[(c*Bsz + b)*D + h] = sr;
    e_im[(c*Bsz + b)*D + h] = si;
}

__global__ __launch_bounds__(256)
void k_scan_combine(const float* __restrict__ nu_log, const float* __restrict__ theta_log,
                    const float* __restrict__ e_re, const float* __restrict__ e_im,
                    float* __restrict__ p_re, float* __restrict__ p_im){
    int h = threadIdx.x;
    int b = blockIdx.x;
    double en = exp((double)nu_log[h]);
    double th = exp((double)theta_log[h]);
    double mag = exp(-en);
    double lr = mag*cos(th), li = mag*sin(th);
    double ar = 1.0, ai = 0.0;               // lam^CL
    for (int i=0;i<CL;i++){
        double nr = ar*lr - ai*li;
        double ni = ar*li + ai*lr;
        ar = nr; ai = ni;
    }
    double sr = 0.0, si = 0.0;
    for (int c=0;c<NC;c++){
        int idx = (c*Bsz + b)*D + h;
        p_re[idx] = (float)sr; p_im[idx] = (float)si;
        double er = e_re[idx], ei = e_im[idx];
        double nr = ar*sr - ai*si + er;
        double ni = ar*si + ai*sr + ei;
        sr = nr; si = ni;
    }
}

// re-scan with prefix; write h IN PLACE over bu planes as bf16 pairs:
//   bu_re dword(col h) <- (bf16(h_re), bf16(h_im))   [hi plane, K-interleaved]
//   bu_im dword(col h) <- (lo residuals)             [lo plane]
__global__ __launch_bounds__(256)
void k_scan_apply(const float* __restrict__ nu_log, const float* __restrict__ theta_log,
                  const float* __restrict__ p_re, const float* __restrict__ p_im,
                  float* __restrict__ bu_re, float* __restrict__ bu_im){
    int h = threadIdx.x;
    int bc = blockIdx.x;
    int b = bc / NC, c = bc % NC;
    float en = expf(nu_log[h]);
    float mag = expf(-en), th = expf(theta_log[h]);
    float lam_re = mag * cosf(th), lam_im = mag * sinf(th);
    int pidx = (c*Bsz + b)*D + h;
    float sr = p_re[pidx], si = p_im[pidx];
    float* pr = bu_re + (size_t)(b*Lsz + c*CL)*D + h;
    float* pi = bu_im + (size_t)(b*Lsz + c*CL)*D + h;
    #pragma unroll 4
    for (int tt=0; tt<CL; tt++){
        float ur = pr[(size_t)tt*D], ui = pi[(size_t)tt*D];
        float nsr = fmaf(lam_re, sr, fmaf(-lam_im, si, ur));
        float nsi = fmaf(lam_re, si, fmaf( lam_im, sr, ui));
        sr = nsr; si = nsi;
        uint16_t rh = bf16_rne(sr), ih = bf16_rne(si);
        uint16_t rl = bf16_rne(sr - bf16_to_f(rh));
        uint16_t il = bf16_rne(si - bf16_to_f(ih));
        *(uint32_t*)&pr[(size_t)tt*D] = (uint32_t)rh | ((uint32_t)ih << 16);
        *(uint32_t*)&pi[(size_t)tt*D] = (uint32_t)rl | ((uint32_t)il << 16);
    }
}

extern "C" void kernel_launch(void* const* d_in, const int* in_sizes, int n_in,
                              void* d_out, int out_size, void* d_ws, size_t ws_size,
                              hipStream_t stream){
    const float* x         = (const float*)d_in[0];
    const float* ln_scale  = (const float*)d_in[1];
    const float* ln_bias   = (const float*)d_in[2];
    const float* nu_log    = (const float*)d_in[3];
    const float* theta_log = (const float*)d_in[4];
    const float* B_re      = (const float*)d_in[5];
    const float* B_im      = (const float*)d_in[6];
    const float* C_re      = (const float*)d_in[7];
    const float* C_im      = (const float*)d_in[8];
    const float* D_skip    = (const float*)d_in[9];
    const float* W         = (const float*)d_in[10];
    const float* bvec      = (const float*)d_in[11];
    float* out = (float*)d_out;

    char* base = (char*)d_ws;
    size_t off = 0;
    auto alloc = [&](size_t bytes)->char*{
        char* p = base + off;
        off += (bytes + 255) & ~(size_t)255;
        return p;
    };
    float*  bu_re = (float*)alloc((size_t)NROWS*D*4);   // later: h hi-plane
    float*  bu_im = (float*)alloc((size_t)NROWS*D*4);   // later: h lo-plane
    short*  xg_hi = (short*)alloc((size_t)NROWS*D*2);   // xhi, later ghi
    short*  xg_lo = (short*)alloc((size_t)NROWS*D*2);   // xlo, later glo
    float*  mu_a  = (float*)alloc((size_t)NROWS*4);
    float*  rs_a  = (float*)alloc((size_t)NROWS*4);
    float*  e_re  = (float*)alloc((size_t)NC*Bsz*D*4);
    float*  e_im  = (float*)alloc((size_t)NC*Bsz*D*4);
    float*  p_re  = (float*)alloc((size_t)NC*Bsz*D*4);
    float*  p_im  = (float*)alloc((size_t)NC*Bsz*D*4);
    float*  t1    = (float*)alloc(512*4);
    float*  t2    = (float*)alloc(512*4);
    short*  b1_hi = (short*)alloc(512*256*2);
    short*  b1_lo = (short*)alloc(512*256*2);
    short*  b2_hi = (short*)alloc(256*512*2);
    short*  b2_lo = (short*)alloc(256*512*2);
    short*  b3_hi = (short*)alloc(256*256*2);
    short*  b3_lo = (short*)alloc(256*256*2);

    k_prep<<<512, 256, 0, stream>>>(B_re, B_im, C_re, C_im, W, ln_scale,
                                    b1_hi, b1_lo, b2_hi, b2_lo, b3_hi, b3_lo);
    k_prep_t<<<2, 256, 0, stream>>>(B_re, B_im, ln_scale, ln_bias, t1, t2);
    k_stats<<<NROWS/16, 256, 0, stream>>>(x, mu_a, rs_a, xg_hi, xg_lo);

    // GEMM1: Bu = gamma*(LN(x) @ B1^T)   (N=512: cols 0-255 re, 256-511 im)
    k_gemm<1><<<(NROWS/128)*4, 256, 0, stream>>>(
        xg_hi, xg_lo, b1_hi, b1_lo, x, mu_a, rs_a, t1, t2, nu_log,
        ln_scale, ln_bias, D_skip, bvec, bu_re, bu_im, nullptr, nullptr);

    k_scan_local<<<Bsz*NC, 256, 0, stream>>>(nu_log, theta_log, bu_re, bu_im, e_re, e_im);
    k_scan_combine<<<Bsz, 256, 0, stream>>>(nu_log, theta_log, e_re, e_im, p_re, p_im);
    k_scan_apply<<<Bsz*NC, 256, 0, stream>>>(nu_log, theta_log, p_re, p_im, bu_re, bu_im);

    // GEMM2: y = Re(h C^T) + Dskip*xn -> gelu -> g planes (alias x-planes)
    k_gemm<2><<<(NROWS/128)*2, 256, 0, stream>>>(
        (const short*)bu_re, (const short*)bu_im, b2_hi, b2_lo, x,
        mu_a, rs_a, t1, t2, nu_log, ln_scale, ln_bias, D_skip, bvec,
        nullptr, nullptr, xg_hi, xg_lo);

    // GEMM3: out = g W^T + b + x
    k_gemm<3><<<(NROWS/128)*2, 256, 0, stream>>>(
        xg_hi, xg_lo, b3_hi, b3_lo, x, mu_a, rs_a, t1, t2, nu_log,
        ln_scale, ln_bias, D_skip, bvec, out, nullptr, nullptr, nullptr);
}

// Round 5
// 399.014 us; speedup vs baseline: 1.2948x; 1.2036x over previous
//
#include <hip/hip_runtime.h>
#include <math.h>
#include <stdint.h>

#define Bsz 8
#define Lsz 8192
#define D 256
#define NROWS (Bsz*Lsz)      // 65536
#define NC 128               // chunks per sequence
#define CL (Lsz/NC)          // 64
#define LN_EPS 1e-6f

typedef float f32x4 __attribute__((ext_vector_type(4)));
typedef short bf16x8 __attribute__((ext_vector_type(8)));
typedef uint32_t __attribute__((address_space(3))) as3_u32;
typedef const uint32_t __attribute__((address_space(1))) as1_u32;

__device__ __forceinline__ float gelu_tanh(float v){
    const float k0 = 0.7978845608028654f;   // sqrt(2/pi)
    const float k1 = 0.044715f;
    float inner = k0 * fmaf(k1*v*v, v, v);
    return 0.5f * v * (1.0f + tanhf(inner));
}
__device__ __forceinline__ uint16_t bf16_rne(float f){
    uint32_t u = __float_as_uint(f);
    return (uint16_t)((u + 0x7fffu + ((u>>16)&1u)) >> 16);
}
__device__ __forceinline__ float bf16_to_f(uint16_t h){
    return __uint_as_float(((uint32_t)h)<<16);
}

// ---- prep: split weights to bf16 hi/lo planes (B-layout [N][K]) ------------
__global__ __launch_bounds__(256)
void k_prep(const float* __restrict__ B_re, const float* __restrict__ B_im,
            const float* __restrict__ C_re, const float* __restrict__ C_im,
            const float* __restrict__ W, const float* __restrict__ ln_scale,
            short* __restrict__ b1_hi, short* __restrict__ b1_lo,
            short* __restrict__ b2_hi, short* __restrict__ b2_lo,
            short* __restrict__ b3_hi, short* __restrict__ b3_lo){
    int i = blockIdx.x*256 + threadIdx.x;   // 131072
    {   // b1 [512][256]
        int n = i >> 8, d = i & 255;
        float v = (n < 256 ? B_re[n*256 + d] : B_im[(n-256)*256 + d]) * ln_scale[d];
        uint16_t hi = bf16_rne(v);
        b1_hi[i] = (short)hi;
        b1_lo[i] = (short)bf16_rne(v - bf16_to_f(hi));
    }
    {   // b2 [256][512], K-interleaved re/im
        int n = i >> 9, k = i & 511, h = k >> 1;
        float v = (k & 1) ? -C_im[n*256 + h] : C_re[n*256 + h];
        uint16_t hi = bf16_rne(v);
        b2_hi[i] = (short)hi;
        b2_lo[i] = (short)bf16_rne(v - bf16_to_f(hi));
    }
    if (i < 256*256){   // b3 [256][256]
        float v = W[i];
        uint16_t hi = bf16_rne(v);
        b3_hi[i] = (short)hi;
        b3_lo[i] = (short)bf16_rne(v - bf16_to_f(hi));
    }
}

__global__ __launch_bounds__(256)
void k_prep_t(const float* __restrict__ B_re, const float* __restrict__ B_im,
              const float* __restrict__ ln_scale, const float* __restrict__ ln_bias,
              float* __restrict__ t1, float* __restrict__ t2){
    int n = blockIdx.x*256 + threadIdx.x;
    if (n >= 512) return;
    const float* src = (n < 256) ? &B_re[n*256] : &B_im[(n-256)*256];
    float s1 = 0.f, s2 = 0.f;
    for (int d = 0; d < 256; d++){
        float b = src[d];
        s1 = fmaf(ln_scale[d], b, s1);
        s2 = fmaf(ln_bias[d],  b, s2);
    }
    t1[n] = s1; t2[n] = s2;
}

// ---- stats: LN (mu, rstd) per row + materialize xhi/xlo bf16 planes --------
__global__ __launch_bounds__(256)
void k_stats(const float* __restrict__ x, float* __restrict__ mu_arr,
             float* __restrict__ rstd_arr, short* __restrict__ xhi,
             short* __restrict__ xlo){
    int r0 = blockIdx.x * 16;
    int t = threadIdx.x;
    int wave = t >> 6, lane = t & 63;
    for (int rr = wave; rr < 16; rr += 4){
        const float* xr = x + (size_t)(r0 + rr) * D;
        float v[4]; float s = 0.f;
        #pragma unroll
        for (int i=0;i<4;i++){ v[i] = xr[lane + 64*i]; s += v[i]; }
        #pragma unroll
        for (int off=32; off; off>>=1) s += __shfl_xor(s, off);
        float mu = s * (1.0f/D);
        float vs = 0.f;
        #pragma unroll
        for (int i=0;i<4;i++){ float dd = v[i]-mu; vs += dd*dd; }
        #pragma unroll
        for (int off=32; off; off>>=1) vs += __shfl_xor(vs, off);
        float rstd = rsqrtf(vs*(1.0f/D) + LN_EPS);
        if (lane == 0){ mu_arr[r0+rr] = mu; rstd_arr[r0+rr] = rstd; }
        size_t rb = (size_t)(r0+rr)*D;
        #pragma unroll
        for (int i=0;i<4;i++){
            int dd = lane + 64*i;
            uint16_t hb = bf16_rne(v[i]);
            xhi[rb+dd] = (short)hb;
            xlo[rb+dd] = (short)bf16_rne(v[i] - bf16_to_f(hb));
        }
    }
}

// ---- 128x256 MFMA GEMM: 3-buffer pipeline, counted vmcnt, 8 waves ----------
// Frag-major LDS (16B chunk c = F*64 + kg*16 + r holds row F*16+r, k-slice kg)
// staged linearly by global_load_lds with pre-permuted per-lane sources.
// Pipeline: stage(t),stage(t+1) ahead; per step: wait vmcnt(6) [own tile-t
// loads done, tile-t+1 in flight] -> s_barrier -> stage(t+2) -> ds_read+MFMA.
#define GLD16(gp, lp) __builtin_amdgcn_global_load_lds((as1_u32*)(gp), (as3_u32*)(lp), 16, 0, 0)

template<int MODE>
__global__ __launch_bounds__(512, 2)
void k_gemm(const short* __restrict__ Ahi_g, const short* __restrict__ Alo_g,
            const short* __restrict__ Bhi_g, const short* __restrict__ Blo_g,
            const float* __restrict__ x,
            const float* __restrict__ mu_arr, const float* __restrict__ rs_arr,
            const float* __restrict__ t1, const float* __restrict__ t2,
            const float* __restrict__ nu_log,
            const float* __restrict__ ln_scale, const float* __restrict__ ln_bias,
            const float* __restrict__ d_skip, const float* __restrict__ bvec,
            float* __restrict__ outA, float* __restrict__ outB,
            short* __restrict__ gh, short* __restrict__ gl){
    constexpr int K   = (MODE==2) ? 512 : 256;
    constexpr int NYB = (MODE==1) ? 2 : 1;
    constexpr int NT  = K/32;
    __shared__ __align__(16) short Ah[3][4096];   // 128 rows x 32 k
    __shared__ __align__(16) short Al[3][4096];
    __shared__ __align__(16) short Bh[3][8192];   // 256 cols x 32 k
    __shared__ __align__(16) short Bl[3][8192];
    const int t = threadIdx.x;
    const int wv = t >> 6, lane = t & 63;
    const int lgrp = lane >> 4, lrow = lane & 15;
    const int r0 = (blockIdx.x / NYB) * 128;
    const int n0 = (blockIdx.x % NYB) * 256;
    const int mr = (wv >> 2) * 64;     // 2 m-waves x 4 n-waves, 64x64 each
    const int nc = (wv & 3) * 64;

    // stage source pointers: wave wv covers F=wv (A) and F=wv, F=8+wv (B)
    const short* pa_h = Ahi_g + (size_t)(r0 + wv*16 + lrow)*K + lgrp*8;
    const short* pa_l = Alo_g + (size_t)(r0 + wv*16 + lrow)*K + lgrp*8;
    const short* pb_h = Bhi_g + (size_t)(n0 + wv*16 + lrow)*K + lgrp*8;
    const short* pb_l = Blo_g + (size_t)(n0 + wv*16 + lrow)*K + lgrp*8;
    const size_t bhop = (size_t)128*K;   // +128 cols (B call 1)

    f32x4 acc[4][4];
    #pragma unroll
    for (int mf=0;mf<4;mf++)
    #pragma unroll
    for (int nf=0;nf<4;nf++) acc[mf][nf] = (f32x4){0.f,0.f,0.f,0.f};

    auto stage = [&](int kt, int buf){
        const int ko = kt*32;
        GLD16(pa_h + ko,        &Ah[buf][wv*512]);
        GLD16(pa_l + ko,        &Al[buf][wv*512]);
        GLD16(pb_h + ko,        &Bh[buf][wv*512]);
        GLD16(pb_h + bhop + ko, &Bh[buf][4096 + wv*512]);
        GLD16(pb_l + ko,        &Bl[buf][wv*512]);
        GLD16(pb_l + bhop + ko, &Bl[buf][4096 + wv*512]);
    };

    stage(0, 0);
    stage(1, 1);
    const int ga = (wv >> 2) * 4, gb = (wv & 3) * 4;
    #pragma unroll
    for (int kt = 0; kt < NT; ++kt){
        if (kt < NT-1) asm volatile("s_waitcnt vmcnt(6)" ::: "memory");
        else           asm volatile("s_waitcnt vmcnt(0)" ::: "memory");
        __builtin_amdgcn_s_barrier();
        __builtin_amdgcn_sched_barrier(0);
        const int buf = kt % 3;
        if (kt+2 < NT) stage(kt+2, (kt+2) % 3);
        bf16x8 ahv[4], alv[4], bhv[4], blv[4];
        #pragma unroll
        for (int mf=0;mf<4;mf++){
            const int c = ((ga+mf)*64 + lgrp*16 + lrow)*8;
            ahv[mf] = *(const bf16x8*)&Ah[buf][c];
            alv[mf] = *(const bf16x8*)&Al[buf][c];
        }
        #pragma unroll
        for (int nf=0;nf<4;nf++){
            const int c = ((gb+nf)*64 + lgrp*16 + lrow)*8;
            bhv[nf] = *(const bf16x8*)&Bh[buf][c];
            blv[nf] = *(const bf16x8*)&Bl[buf][c];
        }
        #pragma unroll
        for (int mf=0;mf<4;mf++)
        #pragma unroll
        for (int nf=0;nf<4;nf++){
            acc[mf][nf] = __builtin_amdgcn_mfma_f32_16x16x32_bf16(ahv[mf], bhv[nf], acc[mf][nf], 0,0,0);
            acc[mf][nf] = __builtin_amdgcn_mfma_f32_16x16x32_bf16(ahv[mf], blv[nf], acc[mf][nf], 0,0,0);
            acc[mf][nf] = __builtin_amdgcn_mfma_f32_16x16x32_bf16(alv[mf], bhv[nf], acc[mf][nf], 0,0,0);
        }
    }

    // ---- epilogue ----
    #pragma unroll
    for (int nf=0; nf<4; nf++){
        const int col = n0 + nc + nf*16 + lrow;
        if (MODE == 1){
            float gam = sqrtf(1.0f - expf(-2.0f*expf(nu_log[col & 255])));
            float t1v = t1[col], t2v = t2[col];
            float* dst = (col < 256) ? outA : outB;
            int c2 = col & 255;
            #pragma unroll
            for (int mf=0;mf<4;mf++){
                #pragma unroll
                for (int j=0;j<4;j++){
                    int row = r0 + mr + mf*16 + lgrp*4 + j;
                    float rs = rs_arr[row], muv = mu_arr[row];
                    dst[(size_t)row*256 + c2] = gam * (rs*acc[mf][nf][j] - rs*muv*t1v + t2v);
                }
            }
        } else if (MODE == 2){
            float dsk = d_skip[col], sc = ln_scale[col], bi = ln_bias[col];
            #pragma unroll
            for (int mf=0;mf<4;mf++){
                #pragma unroll
                for (int j=0;j<4;j++){
                    int row = r0 + mr + mf*16 + lgrp*4 + j;
                    size_t idx = (size_t)row*256 + col;
                    float rs = rs_arr[row], muv = mu_arr[row];
                    float xn = (x[idx] - muv)*rs*sc + bi;
                    float g = gelu_tanh(acc[mf][nf][j] + dsk*xn);
                    uint16_t hb = bf16_rne(g);
                    gh[idx] = (short)hb;
                    gl[idx] = (short)bf16_rne(g - bf16_to_f(hb));
                }
            }
        } else {
            float bb = bvec[col];
            #pragma unroll
            for (int mf=0;mf<4;mf++){
                #pragma unroll
                for (int j=0;j<4;j++){
                    int row = r0 + mr + mf*16 + lgrp*4 + j;
                    size_t idx = (size_t)row*256 + col;
                    outA[idx] = acc[mf][nf][j] + bb + x[idx];
                }
            }
        }
    }
}

// ---- scan kernels ----------------------------------------------------------
__global__ __launch_bounds__(256)
void k_scan_local(const float* __restrict__ nu_log, const float* __restrict__ theta_log,
                  const float* __restrict__ bu_re, const float* __restrict__ bu_im,
                  float* __restrict__ e_re, float* __restrict__ e_im){
    int h = threadIdx.x;
    int bc = blockIdx.x;
    int b = bc / NC, c = bc % NC;
    float en = expf(nu_log[h]);
    float mag = expf(-en), th = expf(theta_log[h]);
    float lam_re = mag * cosf(th), lam_im = mag * sinf(th);
    const float* pr = bu_re + (size_t)(b*Lsz + c*CL)*D + h;
    const float* pi = bu_im + (size_t)(b*Lsz + c*CL)*D + h;
    float sr = 0.f, si = 0.f;
    #pragma unroll 4
    for (int tt=0; tt<CL; tt++){
        float ur = pr[(size_t)tt*D], ui = pi[(size_t)tt*D];
        float nsr = fmaf(lam_re, sr, fmaf(-lam_im, si, ur));
        float nsi = fmaf(lam_re, si, fmaf( lam_im, sr, ui));
        sr = nsr; si = nsi;
    }
    e_re[(c*Bsz + b)*D + h] = sr;
    e_im[(c*Bsz + b)*D + h] = si;
}

__global__ __launch_bounds__(256)
void k_scan_combine(const float* __restrict__ nu_log, const float* __restrict__ theta_log,
                    const float* __restrict__ e_re, const float* __restrict__ e_im,
                    float* __restrict__ p_re, float* __restrict__ p_im){
    int h = threadIdx.x;
    int b = blockIdx.x;
    double en = exp((double)nu_log[h]);
    double th = exp((double)theta_log[h]);
    double mag = exp(-en);
    double lr = mag*cos(th), li = mag*sin(th);
    double ar = 1.0, ai = 0.0;               // lam^CL
    for (int i=0;i<CL;i++){
        double nr = ar*lr - ai*li;
        double ni = ar*li + ai*lr;
        ar = nr; ai = ni;
    }
    double sr = 0.0, si = 0.0;
    for (int c=0;c<NC;c++){
        int idx = (c*Bsz + b)*D + h;
        p_re[idx] = (float)sr; p_im[idx] = (float)si;
        double er = e_re[idx], ei = e_im[idx];
        double nr = ar*sr - ai*si + er;
        double ni = ar*si + ai*sr + ei;
        sr = nr; si = ni;
    }
}

// re-scan with prefix; write h IN PLACE over bu planes as bf16 pairs:
//   bu_re dword(col h) <- (bf16(h_re), bf16(h_im))   [hi plane, K-interleaved]
//   bu_im dword(col h) <- (lo residuals)             [lo plane]
__global__ __launch_bounds__(256)
void k_scan_apply(const float* __restrict__ nu_log, const float* __restrict__ theta_log,
                  const float* __restrict__ p_re, const float* __restrict__ p_im,
                  float* __restrict__ bu_re, float* __restrict__ bu_im){
    int h = threadIdx.x;
    int bc = blockIdx.x;
    int b = bc / NC, c = bc % NC;
    float en = expf(nu_log[h]);
    float mag = expf(-en), th = expf(theta_log[h]);
    float lam_re = mag * cosf(th), lam_im = mag * sinf(th);
    int pidx = (c*Bsz + b)*D + h;
    float sr = p_re[pidx], si = p_im[pidx];
    float* pr = bu_re + (size_t)(b*Lsz + c*CL)*D + h;
    float* pi = bu_im + (size_t)(b*Lsz + c*CL)*D + h;
    #pragma unroll 4
    for (int tt=0; tt<CL; tt++){
        float ur = pr[(size_t)tt*D], ui = pi[(size_t)tt*D];
        float nsr = fmaf(lam_re, sr, fmaf(-lam_im, si, ur));
        float nsi = fmaf(lam_re, si, fmaf( lam_im, sr, ui));
        sr = nsr; si = nsi;
        uint16_t rh = bf16_rne(sr), ih = bf16_rne(si);
        uint16_t rl = bf16_rne(sr - bf16_to_f(rh));
        uint16_t il = bf16_rne(si - bf16_to_f(ih));
        *(uint32_t*)&pr[(size_t)tt*D] = (uint32_t)rh | ((uint32_t)ih << 16);
        *(uint32_t*)&pi[(size_t)tt*D] = (uint32_t)rl | ((uint32_t)il << 16);
    }
}

extern "C" void kernel_launch(void* const* d_in, const int* in_sizes, int n_in,
                              void* d_out, int out_size, void* d_ws, size_t ws_size,
                              hipStream_t stream){
    const float* x         = (const float*)d_in[0];
    const float* ln_scale  = (const float*)d_in[1];
    const float* ln_bias   = (const float*)d_in[2];
    const float* nu_log    = (const float*)d_in[3];
    const float* theta_log = (const float*)d_in[4];
    const float* B_re      = (const float*)d_in[5];
    const float* B_im      = (const float*)d_in[6];
    const float* C_re      = (const float*)d_in[7];
    const float* C_im      = (const float*)d_in[8];
    const float* D_skip    = (const float*)d_in[9];
    const float* W         = (const float*)d_in[10];
    const float* bvec      = (const float*)d_in[11];
    float* out = (float*)d_out;

    char* base = (char*)d_ws;
    size_t off = 0;
    auto alloc = [&](size_t bytes)->char*{
        char* p = base + off;
        off += (bytes + 255) & ~(size_t)255;
        return p;
    };
    float*  bu_re = (float*)alloc((size_t)NROWS*D*4);   // later: h hi-plane
    float*  bu_im = (float*)alloc((size_t)NROWS*D*4);   // later: h lo-plane
    short*  xg_hi = (short*)alloc((size_t)NROWS*D*2);   // xhi, later ghi
    short*  xg_lo = (short*)alloc((size_t)NROWS*D*2);   // xlo, later glo
    float*  mu_a  = (float*)alloc((size_t)NROWS*4);
    float*  rs_a  = (float*)alloc((size_t)NROWS*4);
    float*  e_re  = (float*)alloc((size_t)NC*Bsz*D*4);
    float*  e_im  = (float*)alloc((size_t)NC*Bsz*D*4);
    float*  p_re  = (float*)alloc((size_t)NC*Bsz*D*4);
    float*  p_im  = (float*)alloc((size_t)NC*Bsz*D*4);
    float*  t1    = (float*)alloc(512*4);
    float*  t2    = (float*)alloc(512*4);
    short*  b1_hi = (short*)alloc(512*256*2);
    short*  b1_lo = (short*)alloc(512*256*2);
    short*  b2_hi = (short*)alloc(256*512*2);
    short*  b2_lo = (short*)alloc(256*512*2);
    short*  b3_hi = (short*)alloc(256*256*2);
    short*  b3_lo = (short*)alloc(256*256*2);

    k_prep<<<512, 256, 0, stream>>>(B_re, B_im, C_re, C_im, W, ln_scale,
                                    b1_hi, b1_lo, b2_hi, b2_lo, b3_hi, b3_lo);
    k_prep_t<<<2, 256, 0, stream>>>(B_re, B_im, ln_scale, ln_bias, t1, t2);
    k_stats<<<NROWS/16, 256, 0, stream>>>(x, mu_a, rs_a, xg_hi, xg_lo);

    // GEMM1: Bu = gamma*(LN(x) @ B1^T)   (N=512: cols 0-255 re, 256-511 im)
    k_gemm<1><<<(NROWS/128)*2, 512, 0, stream>>>(
        xg_hi, xg_lo, b1_hi, b1_lo, x, mu_a, rs_a, t1, t2, nu_log,
        ln_scale, ln_bias, D_skip, bvec, bu_re, bu_im, nullptr, nullptr);

    k_scan_local<<<Bsz*NC, 256, 0, stream>>>(nu_log, theta_log, bu_re, bu_im, e_re, e_im);
    k_scan_combine<<<Bsz, 256, 0, stream>>>(nu_log, theta_log, e_re, e_im, p_re, p_im);
    k_scan_apply<<<Bsz*NC, 256, 0, stream>>>(nu_log, theta_log, p_re, p_im, bu_re, bu_im);

    // GEMM2: y = Re(h C^T) + Dskip*xn -> gelu -> g planes (alias x-planes)
    k_gemm<2><<<NROWS/128, 512, 0, stream>>>(
        (const short*)bu_re, (const short*)bu_im, b2_hi, b2_lo, x,
        mu_a, rs_a, t1, t2, nu_log, ln_scale, ln_bias, D_skip, bvec,
        nullptr, nullptr, xg_hi, xg_lo);

    // GEMM3: out = g W^T + b + x
    k_gemm<3><<<NROWS/128, 512, 0, stream>>>(
        xg_hi, xg_lo, b3_hi, b3_lo, x, mu_a, rs_a, t1, t2, nu_log,
        ln_scale, ln_bias, D_skip, bvec, out, nullptr, nullptr, nullptr);
}